// Round 1
// baseline (594.291 us; speedup 1.0000x reference)
//
#include <hip/hip_runtime.h>
#include <cstdint>

#define B_DIM 2
#define S_DIM 2048
#define H_DIM 1024
#define NHEAD 16
#define HDIM 64
#define FF_DIM 4096
#define M_DIM (B_DIM*S_DIM)   // 4096 rows

typedef __bf16 bf16;
typedef __bf16 bf16x8 __attribute__((ext_vector_type(8)));
typedef float  f32x4  __attribute__((ext_vector_type(4)));

// async 16B global->LDS (wave-uniform base + lane*16 on the LDS side)
__device__ __forceinline__ void g2l16(void* lds, const void* g) {
    __builtin_amdgcn_global_load_lds(
        (const __attribute__((address_space(1))) void*)g,
        (__attribute__((address_space(3))) void*)lds,
        16, 0, 0);
}

// ---------------------------------------------------------------------------
// Weight transpose + fp32->bf16:  out[(N,K)] = in[(K,N)]  (in R=K rows, C=N cols)
// ---------------------------------------------------------------------------
__global__ __launch_bounds__(256) void wtrans(const float* __restrict__ in,
                                              bf16* __restrict__ out,
                                              int R, int C) {
    __shared__ float t[32][33];
    int c0 = blockIdx.x * 32, r0 = blockIdx.y * 32;
    int tx = threadIdx.x, ty = threadIdx.y;   // (32,8)
#pragma unroll
    for (int i = 0; i < 4; i++) {
        int r = ty + i * 8;
        t[r][tx] = in[(size_t)(r0 + r) * C + c0 + tx];
    }
    __syncthreads();
#pragma unroll
    for (int i = 0; i < 4; i++) {
        int cc = ty + i * 8;
        out[(size_t)(c0 + cc) * R + r0 + tx] = (bf16)t[tx][cc];
    }
}

// ---------------------------------------------------------------------------
// AdaLN conditioning GEMMs: out{1,2}[b][j] = cond[b]·w{1,2}[:,j] + b{1,2}[j]
// (M=2 rows; VALU is fine, w reads coalesce across j)
// ---------------------------------------------------------------------------
__global__ __launch_bounds__(256) void ada_gemm(const float* __restrict__ cond,
                                                const float* __restrict__ w1, const float* __restrict__ b1,
                                                const float* __restrict__ w2, const float* __restrict__ b2,
                                                float* __restrict__ o1, float* __restrict__ o2) {
    int t = blockIdx.x * 256 + threadIdx.x;      // 8192 threads
    int layer = t >> 12;
    int b = (t >> 11) & 1;
    int j = t & 2047;
    const float* w = layer ? w2 : w1;
    const float* c = cond + (size_t)b * 1024;
    float acc = (layer ? b2 : b1)[j];
    for (int k = 0; k < 1024; k++) acc += c[k] * w[(size_t)k * 2048 + j];
    (layer ? o2 : o1)[b * 2048 + j] = acc;
}

// ---------------------------------------------------------------------------
// Fused LayerNorm + AdaLN modulation: h = (LN(x)*g+b)*(1+scale) + shift  (bf16 out)
// one block per (b,s) row
// ---------------------------------------------------------------------------
__global__ __launch_bounds__(256) void adaln_k(const float* __restrict__ x,
                                               const float* __restrict__ g,
                                               const float* __restrict__ be,
                                               const float* __restrict__ ada,  // (B, 2H): [shift | scale]
                                               bf16* __restrict__ h) {
    int row = blockIdx.x;
    int b = row >> 11;
    int tid = threadIdx.x;
    float4 v = ((const float4*)(x + (size_t)row * H_DIM))[tid];
    float s = v.x + v.y + v.z + v.w;
    __shared__ float sm[4];
#pragma unroll
    for (int m = 32; m >= 1; m >>= 1) s += __shfl_xor(s, m, 64);
    if ((tid & 63) == 0) sm[tid >> 6] = s;
    __syncthreads();
    float mean = (sm[0] + sm[1] + sm[2] + sm[3]) * (1.0f / H_DIM);
    float dx = v.x - mean, dy = v.y - mean, dz = v.z - mean, dw = v.w - mean;
    float s2 = dx * dx + dy * dy + dz * dz + dw * dw;
    __syncthreads();
#pragma unroll
    for (int m = 32; m >= 1; m >>= 1) s2 += __shfl_xor(s2, m, 64);
    if ((tid & 63) == 0) sm[tid >> 6] = s2;
    __syncthreads();
    float var = (sm[0] + sm[1] + sm[2] + sm[3]) * (1.0f / H_DIM);
    float rstd = rsqrtf(var + 1e-5f);
    float4 gv = ((const float4*)g)[tid];
    float4 bv = ((const float4*)be)[tid];
    const float* shp = ada + (size_t)b * 2 * H_DIM;
    float4 shv = ((const float4*)shp)[tid];
    float4 scv = ((const float4*)(shp + H_DIM))[tid];
    bf16* hr = h + (size_t)row * H_DIM + tid * 4;
    hr[0] = (bf16)((dx * rstd * gv.x + bv.x) * (1.0f + scv.x) + shv.x);
    hr[1] = (bf16)((dy * rstd * gv.y + bv.y) * (1.0f + scv.y) + shv.y);
    hr[2] = (bf16)((dz * rstd * gv.z + bv.z) * (1.0f + scv.z) + shv.z);
    hr[3] = (bf16)((dw * rstd * gv.w + bv.w) * (1.0f + scv.w) + shv.w);
}

// ---------------------------------------------------------------------------
// 128x128x32 bf16 MFMA GEMM, C = A(M,K) @ Bt(N,K)^T + bias, fused epilogues
// ---------------------------------------------------------------------------
enum { EPI_ROT = 0, EPI_V = 1, EPI_RES = 2, EPI_GELU = 3 };

template <int EPI>
__global__ __launch_bounds__(256, 2) void gemm_bt(const bf16* __restrict__ A,
                                                  const bf16* __restrict__ Bt,
                                                  const float* __restrict__ bias,
                                                  const float* __restrict__ resid,
                                                  void* __restrict__ outp,
                                                  int M, int N, int K) {
    __shared__ bf16 As[128 * 32];
    __shared__ bf16 Bs[128 * 32];
    int m0 = blockIdx.y * 128, n0 = blockIdx.x * 128;
    int tid = threadIdx.x, wid = tid >> 6, lane = tid & 63;
    int quad = lane >> 4, l16 = lane & 15;
    int wm = (wid >> 1) * 64, wn = (wid & 1) * 64;

    f32x4 acc[4][4];
#pragma unroll
    for (int i = 0; i < 4; i++)
#pragma unroll
        for (int j = 0; j < 4; j++) acc[i][j] = (f32x4){0.f, 0.f, 0.f, 0.f};

    for (int k0 = 0; k0 < K; k0 += 32) {
        __syncthreads();
#pragma unroll
        for (int it = 0; it < 2; it++) {
            int c = it * 256 + wid * 64 + lane;     // 512 16B chunks per operand
            int row = c >> 2, kc = c & 3;
            g2l16(&As[c * 8], A  + (size_t)(m0 + row) * K + k0 + kc * 8);
            g2l16(&Bs[c * 8], Bt + (size_t)(n0 + row) * K + k0 + kc * 8);
        }
        __syncthreads();
        bf16x8 af[4], bfr[4];
#pragma unroll
        for (int i = 0; i < 4; i++) {
            af[i]  = *(const bf16x8*)&As[(wm + i * 16 + l16) * 32 + quad * 8];
            bfr[i] = *(const bf16x8*)&Bs[(wn + i * 16 + l16) * 32 + quad * 8];
        }
#pragma unroll
        for (int mt = 0; mt < 4; mt++)
#pragma unroll
            for (int nt = 0; nt < 4; nt++)
                acc[mt][nt] = __builtin_amdgcn_mfma_f32_16x16x32_bf16(af[mt], bfr[nt], acc[mt][nt], 0, 0, 0);
    }

#pragma unroll
    for (int mt = 0; mt < 4; mt++) {
#pragma unroll
        for (int nt = 0; nt < 4; nt++) {
            int col = n0 + wn + nt * 16 + l16;
            float bc = bias[col];
#pragma unroll
            for (int r = 0; r < 4; r++) {
                int row = m0 + wm + mt * 16 + quad * 4 + r;
                float v = acc[mt][nt][r] + bc;
                if constexpr (EPI == EPI_ROT) {
                    // rotary pair lives on lane^1 (same row, col^1)
                    float pv = __shfl_xor(v, 1, 64);
                    int s = row & (S_DIM - 1);
                    int d = col & (HDIM - 1);
                    int i2 = d >> 1;
                    float ang = (float)s * __expf(-0.2878231366242676f * (float)i2); // ln(10000)/32
                    float sn = __sinf(ang), cs = __cosf(ang);
                    float nv = (d & 1) ? (v * cs + pv * sn) : (v * cs - pv * sn);
                    int bb = row >> 11, hh = col >> 6;
                    ((bf16*)outp)[(((size_t)(bb * NHEAD + hh)) * S_DIM + s) * HDIM + d] = (bf16)nv;
                } else if constexpr (EPI == EPI_V) {
                    int s = row & (S_DIM - 1);
                    int d = col & (HDIM - 1);
                    int bb = row >> 11, hh = col >> 6;
                    ((bf16*)outp)[(((size_t)(bb * NHEAD + hh)) * HDIM + d) * S_DIM + s] = (bf16)v;
                } else if constexpr (EPI == EPI_RES) {
                    ((float*)outp)[(size_t)row * N + col] = v + resid[(size_t)row * N + col];
                } else {  // EPI_GELU (exact)
                    float gl = 0.5f * v * (1.0f + erff(v * 0.70710678118654752f));
                    ((bf16*)outp)[(size_t)row * N + col] = (bf16)gl;
                }
            }
        }
    }
}

// ---------------------------------------------------------------------------
// Flash attention: block = (b,h, 128 q-rows); 4 waves x 32 q-rows; K-tile 128
// Q,K: (B*NH, S, HD) bf16 (rotary applied); Vt: (B*NH, HD, S) bf16
// O: (B, S, H) bf16
// ---------------------------------------------------------------------------
__global__ __launch_bounds__(256, 2) void flash(const bf16* __restrict__ Q,
                                                const bf16* __restrict__ Kg,
                                                const bf16* __restrict__ Vt,
                                                bf16* __restrict__ O) {
    int bh = blockIdx.x;             // 0..31
    int q0 = blockIdx.y * 128;
    int b = bh >> 4, h = bh & (NHEAD - 1);
    int tid = threadIdx.x, wid = tid >> 6, lane = tid & 63;
    int quad = lane >> 4, l16 = lane & 15;

    __shared__ bf16 Ks[128 * 64];      // 16 KB  keys x HD
    __shared__ bf16 Vs[64 * 128];      // 16 KB  HD x keys
    __shared__ bf16 Ps[4][32 * 128];   // 32 KB  per-wave P round-trip

    const bf16* Qb = Q  + ((size_t)bh * S_DIM + q0 + wid * 32) * HDIM;
    const bf16* Kb = Kg + (size_t)bh * S_DIM * HDIM;
    const bf16* Vb = Vt + (size_t)bh * HDIM * S_DIM;

    // Q A-fragments, held in registers for the whole kernel
    bf16x8 qf[2][2];
#pragma unroll
    for (int mt = 0; mt < 2; mt++)
#pragma unroll
        for (int ks = 0; ks < 2; ks++)
            qf[mt][ks] = *(const bf16x8*)(Qb + (size_t)(mt * 16 + l16) * HDIM + ks * 32 + quad * 8);

    f32x4 oacc[2][4];
#pragma unroll
    for (int i = 0; i < 2; i++)
#pragma unroll
        for (int j = 0; j < 4; j++) oacc[i][j] = (f32x4){0.f, 0.f, 0.f, 0.f};
    float mi[2][4], li[2][4];
#pragma unroll
    for (int i = 0; i < 2; i++)
#pragma unroll
        for (int r = 0; r < 4; r++) { mi[i][r] = -1e30f; li[i][r] = 0.f; }

    for (int kt = 0; kt < S_DIM; kt += 128) {
        __syncthreads();
#pragma unroll
        for (int it = 0; it < 4; it++) {
            int c = it * 256 + wid * 64 + lane;   // 1024 chunks each
            g2l16(&Ks[c * 8], Kb + (size_t)(kt + (c >> 3)) * HDIM + (c & 7) * 8);
            g2l16(&Vs[c * 8], Vb + (size_t)(c >> 4) * S_DIM + kt + (c & 15) * 8);
        }
        __syncthreads();

        // S = Q @ K^T
        f32x4 sacc[2][8];
#pragma unroll
        for (int i = 0; i < 2; i++)
#pragma unroll
            for (int j = 0; j < 8; j++) sacc[i][j] = (f32x4){0.f, 0.f, 0.f, 0.f};
#pragma unroll
        for (int ks = 0; ks < 2; ks++)
#pragma unroll
            for (int nt = 0; nt < 8; nt++) {
                bf16x8 kf = *(const bf16x8*)&Ks[(nt * 16 + l16) * 64 + ks * 32 + quad * 8];
#pragma unroll
                for (int mt = 0; mt < 2; mt++)
                    sacc[mt][nt] = __builtin_amdgcn_mfma_f32_16x16x32_bf16(qf[mt][ks], kf, sacc[mt][nt], 0, 0, 0);
            }

        // online softmax (scale 1/sqrt(64) = 0.125)
        float al[2][4];
#pragma unroll
        for (int mt = 0; mt < 2; mt++) {
#pragma unroll
            for (int r = 0; r < 4; r++) {
                float mx = -1e30f;
#pragma unroll
                for (int nt = 0; nt < 8; nt++) {
                    sacc[mt][nt][r] *= 0.125f;
                    mx = fmaxf(mx, sacc[mt][nt][r]);
                }
#pragma unroll
                for (int m = 8; m >= 1; m >>= 1) mx = fmaxf(mx, __shfl_xor(mx, m, 64));
                float mn = fmaxf(mi[mt][r], mx);
                al[mt][r] = __expf(mi[mt][r] - mn);
                mi[mt][r] = mn;
                float rs = 0.f;
#pragma unroll
                for (int nt = 0; nt < 8; nt++) {
                    float pp = __expf(sacc[mt][nt][r] - mn);
                    sacc[mt][nt][r] = pp;
                    rs += pp;
                }
#pragma unroll
                for (int m = 8; m >= 1; m >>= 1) rs += __shfl_xor(rs, m, 64);
                li[mt][r] = li[mt][r] * al[mt][r] + rs;
            }
        }

        // P: C-layout -> LDS -> A-layout; rescale O
#pragma unroll
        for (int mt = 0; mt < 2; mt++)
#pragma unroll
            for (int nt = 0; nt < 8; nt++)
#pragma unroll
                for (int r = 0; r < 4; r++)
                    Ps[wid][(mt * 16 + quad * 4 + r) * 128 + nt * 16 + l16] = (bf16)sacc[mt][nt][r];
#pragma unroll
        for (int mt = 0; mt < 2; mt++)
#pragma unroll
            for (int nt = 0; nt < 4; nt++)
#pragma unroll
                for (int r = 0; r < 4; r++) oacc[mt][nt][r] *= al[mt][r];

        // O += P @ V
#pragma unroll
        for (int kk = 0; kk < 4; kk++) {
            bf16x8 vf[4];
#pragma unroll
            for (int nt = 0; nt < 4; nt++)
                vf[nt] = *(const bf16x8*)&Vs[(nt * 16 + l16) * 128 + kk * 32 + quad * 8];
#pragma unroll
            for (int mt = 0; mt < 2; mt++) {
                bf16x8 pf = *(const bf16x8*)&Ps[wid][(mt * 16 + l16) * 128 + kk * 32 + quad * 8];
#pragma unroll
                for (int nt = 0; nt < 4; nt++)
                    oacc[mt][nt] = __builtin_amdgcn_mfma_f32_16x16x32_bf16(pf, vf[nt], oacc[mt][nt], 0, 0, 0);
            }
        }
    }

#pragma unroll
    for (int mt = 0; mt < 2; mt++)
#pragma unroll
        for (int r = 0; r < 4; r++) {
            float inv = 1.0f / li[mt][r];
            int s = q0 + wid * 32 + mt * 16 + quad * 4 + r;
#pragma unroll
            for (int nt = 0; nt < 4; nt++) {
                int d = nt * 16 + l16;
                O[((size_t)b * S_DIM + s) * H_DIM + h * HDIM + d] = (bf16)(oacc[mt][nt][r] * inv);
            }
        }
}

// ---------------------------------------------------------------------------
extern "C" void kernel_launch(void* const* d_in, const int* in_sizes, int n_in,
                              void* d_out, int out_size, void* d_ws, size_t ws_size,
                              hipStream_t stream) {
    const float* x     = (const float*)d_in[0];
    const float* cond  = (const float*)d_in[1];
    // d_in[2] attn_mask: all-ones by construction -> no-op in softmax; ignored
    const float* wq    = (const float*)d_in[3];
    const float* bq    = (const float*)d_in[4];
    const float* wk    = (const float*)d_in[5];
    const float* bk    = (const float*)d_in[6];
    const float* wv    = (const float*)d_in[7];
    const float* bv    = (const float*)d_in[8];
    const float* wo    = (const float*)d_in[9];
    const float* bo    = (const float*)d_in[10];
    const float* ln1g  = (const float*)d_in[11];
    const float* ln1b  = (const float*)d_in[12];
    const float* ada1w = (const float*)d_in[13];
    const float* ada1b = (const float*)d_in[14];
    const float* ln2g  = (const float*)d_in[15];
    const float* ln2b  = (const float*)d_in[16];
    const float* ada2w = (const float*)d_in[17];
    const float* ada2b = (const float*)d_in[18];
    const float* fw1   = (const float*)d_in[19];
    const float* fb1   = (const float*)d_in[20];
    const float* fw2   = (const float*)d_in[21];
    const float* fb2   = (const float*)d_in[22];

    char* p = (char*)d_ws;
    auto take = [&](size_t n) { char* r = p; p += (n + 255) & ~(size_t)255; return (void*)r; };

    bf16* wtq  = (bf16*)take((size_t)H_DIM * H_DIM * 2);
    bf16* wtk  = (bf16*)take((size_t)H_DIM * H_DIM * 2);
    bf16* wtv  = (bf16*)take((size_t)H_DIM * H_DIM * 2);
    bf16* wto  = (bf16*)take((size_t)H_DIM * H_DIM * 2);
    bf16* wtf1 = (bf16*)take((size_t)FF_DIM * H_DIM * 2);   // (N=4096, K=1024)
    bf16* wtf2 = (bf16*)take((size_t)H_DIM * FF_DIM * 2);   // (N=1024, K=4096)
    float* ada1o = (float*)take((size_t)B_DIM * 2 * H_DIM * 4);
    float* ada2o = (float*)take((size_t)B_DIM * 2 * H_DIM * 4);
    bf16* h    = (bf16*)take((size_t)M_DIM * H_DIM * 2);    // h1, later h2
    bf16* qr   = (bf16*)take((size_t)M_DIM * H_DIM * 2);    // (B,NH,S,HD)
    bf16* kr   = (bf16*)take((size_t)M_DIM * H_DIM * 2);
    bf16* vtb  = (bf16*)take((size_t)M_DIM * H_DIM * 2);    // (B,NH,HD,S)
    bf16* attn = (bf16*)take((size_t)M_DIM * H_DIM * 2);    // (B,S,H)
    float* x2  = (float*)take((size_t)M_DIM * H_DIM * 4);
    bf16* ff1b = qr;  // 32MB GELU buffer aliases qr|kr|vtb|attn (dead by FF1 time)

    dim3 tb(32, 8);
    wtrans<<<dim3(32, 32),  tb, 0, stream>>>(wq,  wtq,  1024, 1024);
    wtrans<<<dim3(32, 32),  tb, 0, stream>>>(wk,  wtk,  1024, 1024);
    wtrans<<<dim3(32, 32),  tb, 0, stream>>>(wv,  wtv,  1024, 1024);
    wtrans<<<dim3(32, 32),  tb, 0, stream>>>(wo,  wto,  1024, 1024);
    wtrans<<<dim3(128, 32), tb, 0, stream>>>(fw1, wtf1, 1024, 4096);
    wtrans<<<dim3(32, 128), tb, 0, stream>>>(fw2, wtf2, 4096, 1024);

    ada_gemm<<<32, 256, 0, stream>>>(cond, ada1w, ada1b, ada2w, ada2b, ada1o, ada2o);
    adaln_k<<<M_DIM, 256, 0, stream>>>(x, ln1g, ln1b, ada1o, h);

    gemm_bt<EPI_ROT><<<dim3(8, 32), 256, 0, stream>>>(h, wtq, bq, nullptr, qr,  M_DIM, H_DIM, H_DIM);
    gemm_bt<EPI_ROT><<<dim3(8, 32), 256, 0, stream>>>(h, wtk, bk, nullptr, kr,  M_DIM, H_DIM, H_DIM);
    gemm_bt<EPI_V>  <<<dim3(8, 32), 256, 0, stream>>>(h, wtv, bv, nullptr, vtb, M_DIM, H_DIM, H_DIM);

    flash<<<dim3(32, 16), 256, 0, stream>>>(qr, kr, vtb, attn);

    gemm_bt<EPI_RES><<<dim3(8, 32), 256, 0, stream>>>(attn, wto, bo, x, x2, M_DIM, H_DIM, H_DIM);

    adaln_k<<<M_DIM, 256, 0, stream>>>(x2, ln2g, ln2b, ada2o, h);

    gemm_bt<EPI_GELU><<<dim3(32, 32), 256, 0, stream>>>(h, wtf1, fb1, nullptr, ff1b, M_DIM, FF_DIM, H_DIM);
    gemm_bt<EPI_RES> <<<dim3(8, 32),  256, 0, stream>>>(ff1b, wtf2, fb2, x2, (float*)d_out, M_DIM, H_DIM, FF_DIM);

    (void)in_sizes; (void)n_in; (void)out_size; (void)ws_size;
}

// Round 2
// 494.325 us; speedup vs baseline: 1.2022x; 1.2022x over previous
//
#include <hip/hip_runtime.h>
#include <cstdint>

#define B_DIM 2
#define S_DIM 2048
#define H_DIM 1024
#define NHEAD 16
#define HDIM 64
#define FF_DIM 4096
#define M_DIM (B_DIM*S_DIM)   // 4096 rows

typedef __bf16 bf16;
typedef _Float16 f16;
typedef __bf16 bf16x8 __attribute__((ext_vector_type(8)));
typedef __bf16 bf16x4 __attribute__((ext_vector_type(4)));
typedef _Float16 f16x4 __attribute__((ext_vector_type(4)));
typedef float  f32x4  __attribute__((ext_vector_type(4)));

#define QK_SCALE 0.18033688011112042f   // 0.125 * log2(e): S is in log2 units

#if __has_builtin(__builtin_amdgcn_exp2f)
#define EXP2F(x) __builtin_amdgcn_exp2f(x)
#else
#define EXP2F(x) __expf(0.69314718055994531f*(x))
#endif

// async 16B global->LDS (wave-uniform base + lane*16 on the LDS side)
__device__ __forceinline__ void g2l16(void* lds, const void* g) {
    __builtin_amdgcn_global_load_lds(
        (const __attribute__((address_space(1))) void*)g,
        (__attribute__((address_space(3))) void*)lds,
        16, 0, 0);
}

// ---------------------------------------------------------------------------
// Weight transpose + fp32->bf16:  out[(N,K)] = in[(K,N)]
// ---------------------------------------------------------------------------
__global__ __launch_bounds__(256) void wtrans(const float* __restrict__ in,
                                              bf16* __restrict__ out,
                                              int R, int C) {
    __shared__ float t[32][33];
    int c0 = blockIdx.x * 32, r0 = blockIdx.y * 32;
    int tx = threadIdx.x, ty = threadIdx.y;   // (32,8)
#pragma unroll
    for (int i = 0; i < 4; i++) {
        int r = ty + i * 8;
        t[r][tx] = in[(size_t)(r0 + r) * C + c0 + tx];
    }
    __syncthreads();
#pragma unroll
    for (int i = 0; i < 4; i++) {
        int cc = ty + i * 8;
        out[(size_t)(c0 + cc) * R + r0 + tx] = (bf16)t[tx][cc];
    }
}

// ---------------------------------------------------------------------------
// AdaLN conditioning GEMMs (M=2): out{1,2}[b][j] = cond[b]·w{1,2}[:,j] + b{1,2}[j]
// ---------------------------------------------------------------------------
__global__ __launch_bounds__(256) void ada_gemm(const float* __restrict__ cond,
                                                const float* __restrict__ w1, const float* __restrict__ b1,
                                                const float* __restrict__ w2, const float* __restrict__ b2,
                                                float* __restrict__ o1, float* __restrict__ o2) {
    int t = blockIdx.x * 256 + threadIdx.x;
    int layer = t >> 12;
    int b = (t >> 11) & 1;
    int j = t & 2047;
    const float* w = layer ? w2 : w1;
    const float* c = cond + (size_t)b * 1024;
    float acc = (layer ? b2 : b1)[j];
    for (int k = 0; k < 1024; k++) acc += c[k] * w[(size_t)k * 2048 + j];
    (layer ? o2 : o1)[b * 2048 + j] = acc;
}

// ---------------------------------------------------------------------------
// Fused LayerNorm + AdaLN modulation (bf16 out); one block per (b,s) row
// ---------------------------------------------------------------------------
__global__ __launch_bounds__(256) void adaln_k(const float* __restrict__ x,
                                               const float* __restrict__ g,
                                               const float* __restrict__ be,
                                               const float* __restrict__ ada,
                                               bf16* __restrict__ h) {
    int row = blockIdx.x;
    int b = row >> 11;
    int tid = threadIdx.x;
    float4 v = ((const float4*)(x + (size_t)row * H_DIM))[tid];
    float s = v.x + v.y + v.z + v.w;
    __shared__ float sm[4];
#pragma unroll
    for (int m = 32; m >= 1; m >>= 1) s += __shfl_xor(s, m, 64);
    if ((tid & 63) == 0) sm[tid >> 6] = s;
    __syncthreads();
    float mean = (sm[0] + sm[1] + sm[2] + sm[3]) * (1.0f / H_DIM);
    float dx = v.x - mean, dy = v.y - mean, dz = v.z - mean, dw = v.w - mean;
    float s2 = dx * dx + dy * dy + dz * dz + dw * dw;
    __syncthreads();
#pragma unroll
    for (int m = 32; m >= 1; m >>= 1) s2 += __shfl_xor(s2, m, 64);
    if ((tid & 63) == 0) sm[tid >> 6] = s2;
    __syncthreads();
    float var = (sm[0] + sm[1] + sm[2] + sm[3]) * (1.0f / H_DIM);
    float rstd = rsqrtf(var + 1e-5f);
    float4 gv = ((const float4*)g)[tid];
    float4 bv = ((const float4*)be)[tid];
    const float* shp = ada + (size_t)b * 2 * H_DIM;
    float4 shv = ((const float4*)shp)[tid];
    float4 scv = ((const float4*)(shp + H_DIM))[tid];
    bf16* hr = h + (size_t)row * H_DIM + tid * 4;
    hr[0] = (bf16)((dx * rstd * gv.x + bv.x) * (1.0f + scv.x) + shv.x);
    hr[1] = (bf16)((dy * rstd * gv.y + bv.y) * (1.0f + scv.y) + shv.y);
    hr[2] = (bf16)((dz * rstd * gv.z + bv.z) * (1.0f + scv.z) + shv.z);
    hr[3] = (bf16)((dw * rstd * gv.w + bv.w) * (1.0f + scv.w) + shv.w);
}

// ---------------------------------------------------------------------------
// 128x128x32 bf16 MFMA GEMM, C = A(M,K) @ Bt(N,K)^T + bias, fused epilogues
// ---------------------------------------------------------------------------
enum { EPI_RES = 0, EPI_GELU = 1 };

template <int EPI>
__global__ __launch_bounds__(256, 2) void gemm_bt(const bf16* __restrict__ A,
                                                  const bf16* __restrict__ Bt,
                                                  const float* __restrict__ bias,
                                                  const float* __restrict__ resid,
                                                  void* __restrict__ outp,
                                                  int M, int N, int K) {
    __shared__ bf16 As[128 * 32];
    __shared__ bf16 Bs[128 * 32];
    int m0 = blockIdx.y * 128, n0 = blockIdx.x * 128;
    int tid = threadIdx.x, wid = tid >> 6, lane = tid & 63;
    int quad = lane >> 4, l16 = lane & 15;
    int wm = (wid >> 1) * 64, wn = (wid & 1) * 64;

    f32x4 acc[4][4];
#pragma unroll
    for (int i = 0; i < 4; i++)
#pragma unroll
        for (int j = 0; j < 4; j++) acc[i][j] = (f32x4){0.f, 0.f, 0.f, 0.f};

    for (int k0 = 0; k0 < K; k0 += 32) {
        __syncthreads();
#pragma unroll
        for (int it = 0; it < 2; it++) {
            int c = it * 256 + wid * 64 + lane;
            int row = c >> 2, kc = c & 3;
            g2l16(&As[c * 8], A  + (size_t)(m0 + row) * K + k0 + kc * 8);
            g2l16(&Bs[c * 8], Bt + (size_t)(n0 + row) * K + k0 + kc * 8);
        }
        __syncthreads();
        bf16x8 af[4], bfr[4];
#pragma unroll
        for (int i = 0; i < 4; i++) {
            af[i]  = *(const bf16x8*)&As[(wm + i * 16 + l16) * 32 + quad * 8];
            bfr[i] = *(const bf16x8*)&Bs[(wn + i * 16 + l16) * 32 + quad * 8];
        }
#pragma unroll
        for (int mt = 0; mt < 4; mt++)
#pragma unroll
            for (int nt = 0; nt < 4; nt++)
                acc[mt][nt] = __builtin_amdgcn_mfma_f32_16x16x32_bf16(af[mt], bfr[nt], acc[mt][nt], 0, 0, 0);
    }

#pragma unroll
    for (int mt = 0; mt < 4; mt++) {
#pragma unroll
        for (int nt = 0; nt < 4; nt++) {
            int col = n0 + wn + nt * 16 + l16;
            float bc = bias[col];
#pragma unroll
            for (int r = 0; r < 4; r++) {
                int row = m0 + wm + mt * 16 + quad * 4 + r;
                float v = acc[mt][nt][r] + bc;
                if constexpr (EPI == EPI_RES) {
                    ((float*)outp)[(size_t)row * N + col] = v + resid[(size_t)row * N + col];
                } else {  // exact GELU
                    float gl = 0.5f * v * (1.0f + erff(v * 0.70710678118654752f));
                    ((bf16*)outp)[(size_t)row * N + col] = (bf16)gl;
                }
            }
        }
    }
}

// ---------------------------------------------------------------------------
// Merged QKV GEMM: A(4096,1024) @ Wqkv^T(3072,1024) -> Q(rot*scale), K(rot), V(f16,T)
// grid (24, 32)
// ---------------------------------------------------------------------------
__global__ __launch_bounds__(256, 2) void gemm_qkv(const bf16* __restrict__ A,
                                                   const bf16* __restrict__ Bt,
                                                   const float* __restrict__ bq,
                                                   const float* __restrict__ bk,
                                                   const float* __restrict__ bv,
                                                   bf16* __restrict__ qr,
                                                   bf16* __restrict__ kr,
                                                   f16* __restrict__ vtf) {
    __shared__ bf16 As[128 * 32];
    __shared__ bf16 Bs[128 * 32];
    const int K = H_DIM;
    int m0 = blockIdx.y * 128, n0 = blockIdx.x * 128;
    int tid = threadIdx.x, wid = tid >> 6, lane = tid & 63;
    int quad = lane >> 4, l16 = lane & 15;
    int wm = (wid >> 1) * 64, wn = (wid & 1) * 64;

    f32x4 acc[4][4];
#pragma unroll
    for (int i = 0; i < 4; i++)
#pragma unroll
        for (int j = 0; j < 4; j++) acc[i][j] = (f32x4){0.f, 0.f, 0.f, 0.f};

    for (int k0 = 0; k0 < K; k0 += 32) {
        __syncthreads();
#pragma unroll
        for (int it = 0; it < 2; it++) {
            int c = it * 256 + wid * 64 + lane;
            int row = c >> 2, kc = c & 3;
            g2l16(&As[c * 8], A  + (size_t)(m0 + row) * K + k0 + kc * 8);
            g2l16(&Bs[c * 8], Bt + (size_t)(n0 + row) * K + k0 + kc * 8);
        }
        __syncthreads();
        bf16x8 af[4], bfr[4];
#pragma unroll
        for (int i = 0; i < 4; i++) {
            af[i]  = *(const bf16x8*)&As[(wm + i * 16 + l16) * 32 + quad * 8];
            bfr[i] = *(const bf16x8*)&Bs[(wn + i * 16 + l16) * 32 + quad * 8];
        }
#pragma unroll
        for (int mt = 0; mt < 4; mt++)
#pragma unroll
            for (int nt = 0; nt < 4; nt++)
                acc[mt][nt] = __builtin_amdgcn_mfma_f32_16x16x32_bf16(af[mt], bfr[nt], acc[mt][nt], 0, 0, 0);
    }

#pragma unroll
    for (int mt = 0; mt < 4; mt++) {
#pragma unroll
        for (int nt = 0; nt < 4; nt++) {
            int col = n0 + wn + nt * 16 + l16;          // 0..3071
            int sec = col >> 10;                        // uniform across lanes
            int cc  = col & 1023;
            float bc = (sec == 0) ? bq[cc] : (sec == 1) ? bk[cc] : bv[cc];
            int hh = cc >> 6, d = cc & 63;
#pragma unroll
            for (int r = 0; r < 4; r++) {
                int row = m0 + wm + mt * 16 + quad * 4 + r;
                int bb = row >> 11, s = row & (S_DIM - 1);
                float v = acc[mt][nt][r] + bc;
                if (sec < 2) {
                    float pv = __shfl_xor(v, 1, 64);    // rotary pair = col^1 (lane^1)
                    int i2 = d >> 1;
                    float ang = (float)s * __expf(-0.2878231366242676f * (float)i2); // ln(1e4)/32
                    float sn = __sinf(ang), cs = __cosf(ang);
                    float nv = (d & 1) ? (v * cs + pv * sn) : (v * cs - pv * sn);
                    if (sec == 0) nv *= QK_SCALE;
                    bf16* dst = sec ? kr : qr;
                    dst[(((size_t)(bb * NHEAD + hh)) * S_DIM + s) * HDIM + d] = (bf16)nv;
                } else {
                    vtf[(((size_t)(bb * NHEAD + hh)) * HDIM + d) * S_DIM + s] = (f16)v;
                }
            }
        }
    }
}

// ---------------------------------------------------------------------------
// Flash attention v2 (transposed-S): block = (b,h, 128 q); 4 waves x 32 q.
// Computes St = K·Q^T so softmaxed P stays in registers as the B-operand of
// mfma_f32_16x16x16f16 (Ot = Vt·Pt). Ks/Vs are XOR-chunk-swizzled to put
// every LDS read at the bank floor.
// Q,K: (B*NH, S, HD) bf16 (rotary; Q pre-scaled by 0.125*log2e); Vt: (B*NH, HD, S) f16
// ---------------------------------------------------------------------------
__global__ __launch_bounds__(256, 2) void flash(const bf16* __restrict__ Q,
                                                const bf16* __restrict__ Kg,
                                                const f16* __restrict__ Vt,
                                                bf16* __restrict__ O) {
    int bh = blockIdx.x;
    int q0 = blockIdx.y * 128;
    int b = bh >> 4, h = bh & (NHEAD - 1);
    int tid = threadIdx.x, wid = tid >> 6, lane = tid & 63;
    int quad = lane >> 4, l16 = lane & 15;
    int j3 = l16 & 7;

    __shared__ bf16 Ks[128 * 64];   // 16 KB, key-major, 8 chunks/row, swizzled
    __shared__ f16  Vs[64 * 128];   // 16 KB, d-major,  16 chunks/row, swizzled

    const bf16* Qb = Q  + ((size_t)bh * S_DIM + q0 + wid * 32) * HDIM;
    const bf16* Kb = Kg + (size_t)bh * S_DIM * HDIM;
    const f16*  Vb = Vt + (size_t)bh * HDIM * S_DIM;

    // Q as B-operand fragments (n=q on l16, k=d on quad*8+j) — held all kernel
    bf16x8 qf[2][2];
#pragma unroll
    for (int qt = 0; qt < 2; qt++)
#pragma unroll
        for (int ks = 0; ks < 2; ks++)
            qf[qt][ks] = *(const bf16x8*)(Qb + (size_t)(qt * 16 + l16) * HDIM + ks * 32 + quad * 8);

    f32x4 oacc[4][2];   // Ot[d=mt*16+quad*4+r][q=qt*16+l16]
#pragma unroll
    for (int i = 0; i < 4; i++)
#pragma unroll
        for (int j = 0; j < 2; j++) oacc[i][j] = (f32x4){0.f, 0.f, 0.f, 0.f};
    float mi[2] = {-1e30f, -1e30f}, li[2] = {0.f, 0.f};

    for (int kt = 0; kt < S_DIM; kt += 128) {
        __syncthreads();
#pragma unroll
        for (int it = 0; it < 4; it++) {
            int c = it * 256 + tid;
            int krow = c >> 3, kp = c & 7;                 // Ks: phys chunk kp holds logical kp^(row&7)
            g2l16(&Ks[c * 8], Kb + (size_t)(kt + krow) * HDIM + (kp ^ (krow & 7)) * 8);
            int vrow = c >> 4, vp = c & 15;                // Vs: same swizzle, 16 chunks/row
            g2l16(&Vs[c * 8], Vb + (size_t)vrow * S_DIM + kt + ((vp ^ (vrow & 7)) * 8));
        }
        __syncthreads();

        // St = K·Q^T  (row=key, col=q)
        f32x4 sacc[8][2];
#pragma unroll
        for (int i = 0; i < 8; i++)
#pragma unroll
            for (int j = 0; j < 2; j++) sacc[i][j] = (f32x4){0.f, 0.f, 0.f, 0.f};
#pragma unroll
        for (int nt = 0; nt < 8; nt++)
#pragma unroll
            for (int ks = 0; ks < 2; ks++) {
                int row = nt * 16 + l16;
                int pc = (ks * 4 + quad) ^ j3;
                bf16x8 kf = *(const bf16x8*)&Ks[row * 64 + pc * 8];
#pragma unroll
                for (int qt = 0; qt < 2; qt++)
                    sacc[nt][qt] = __builtin_amdgcn_mfma_f32_16x16x32_bf16(kf, qf[qt][ks], sacc[nt][qt], 0, 0, 0);
            }

        // online softmax over keys (in-lane nt,r + cross-quad); S already in log2 units
        float al[2];
#pragma unroll
        for (int qt = 0; qt < 2; qt++) {
            float mx = -1e30f;
#pragma unroll
            for (int nt = 0; nt < 8; nt++)
#pragma unroll
                for (int r = 0; r < 4; r++) mx = fmaxf(mx, sacc[nt][qt][r]);
            mx = fmaxf(mx, __shfl_xor(mx, 16, 64));
            mx = fmaxf(mx, __shfl_xor(mx, 32, 64));
            float mn = fmaxf(mi[qt], mx);
            al[qt] = EXP2F(mi[qt] - mn);
            mi[qt] = mn;
            float rs = 0.f;
#pragma unroll
            for (int nt = 0; nt < 8; nt++)
#pragma unroll
                for (int r = 0; r < 4; r++) {
                    float p = EXP2F(sacc[nt][qt][r] - mn);
                    sacc[nt][qt][r] = p;
                    rs += p;
                }
            rs += __shfl_xor(rs, 16, 64);
            rs += __shfl_xor(rs, 32, 64);
            li[qt] = li[qt] * al[qt] + rs;
        }
#pragma unroll
        for (int mt = 0; mt < 4; mt++)
#pragma unroll
            for (int qt = 0; qt < 2; qt++)
#pragma unroll
                for (int r = 0; r < 4; r++) oacc[mt][qt][r] *= al[qt];

        // Ot += Vt·Pt  (P direct from registers as B-operand, K=16 f16 MFMA)
#pragma unroll
        for (int kc = 0; kc < 8; kc++) {
            f16x4 pf[2];
#pragma unroll
            for (int qt = 0; qt < 2; qt++)
#pragma unroll
                for (int r = 0; r < 4; r++) pf[qt][r] = (f16)sacc[kc][qt][r];
#pragma unroll
            for (int mt = 0; mt < 4; mt++) {
                int row = mt * 16 + l16;
                int pc = (2 * kc + (quad >> 1)) ^ j3;
                f16x4 vf = *(const f16x4*)&Vs[row * 128 + pc * 8 + (quad & 1) * 4];
#pragma unroll
                for (int qt = 0; qt < 2; qt++)
                    oacc[mt][qt] = __builtin_amdgcn_mfma_f32_16x16x16f16(vf, pf[qt], oacc[mt][qt], 0, 0, 0);
            }
        }
    }

    float inv[2] = {1.0f / li[0], 1.0f / li[1]};
#pragma unroll
    for (int mt = 0; mt < 4; mt++)
#pragma unroll
        for (int qt = 0; qt < 2; qt++) {
            int q = q0 + wid * 32 + qt * 16 + l16;
            int d = mt * 16 + quad * 4;
            bf16x4 o;
#pragma unroll
            for (int r = 0; r < 4; r++) o[r] = (bf16)(oacc[mt][qt][r] * inv[qt]);
            *(bf16x4*)(O + ((size_t)b * S_DIM + q) * H_DIM + h * HDIM + d) = o;
        }
}

// ---------------------------------------------------------------------------
extern "C" void kernel_launch(void* const* d_in, const int* in_sizes, int n_in,
                              void* d_out, int out_size, void* d_ws, size_t ws_size,
                              hipStream_t stream) {
    const float* x     = (const float*)d_in[0];
    const float* cond  = (const float*)d_in[1];
    // d_in[2] attn_mask: all-ones by construction -> softmax no-op; ignored
    const float* wq    = (const float*)d_in[3];
    const float* bq    = (const float*)d_in[4];
    const float* wk    = (const float*)d_in[5];
    const float* bk    = (const float*)d_in[6];
    const float* wv    = (const float*)d_in[7];
    const float* bv    = (const float*)d_in[8];
    const float* wo    = (const float*)d_in[9];
    const float* bo    = (const float*)d_in[10];
    const float* ln1g  = (const float*)d_in[11];
    const float* ln1b  = (const float*)d_in[12];
    const float* ada1w = (const float*)d_in[13];
    const float* ada1b = (const float*)d_in[14];
    const float* ln2g  = (const float*)d_in[15];
    const float* ln2b  = (const float*)d_in[16];
    const float* ada2w = (const float*)d_in[17];
    const float* ada2b = (const float*)d_in[18];
    const float* fw1   = (const float*)d_in[19];
    const float* fb1   = (const float*)d_in[20];
    const float* fw2   = (const float*)d_in[21];
    const float* fb2   = (const float*)d_in[22];

    char* p = (char*)d_ws;
    auto take = [&](size_t n) { char* r = p; p += (n + 255) & ~(size_t)255; return (void*)r; };

    bf16* wqkv = (bf16*)take((size_t)3 * H_DIM * H_DIM * 2);   // (3072,1024)
    bf16* wto  = (bf16*)take((size_t)H_DIM * H_DIM * 2);
    bf16* wtf1 = (bf16*)take((size_t)FF_DIM * H_DIM * 2);
    bf16* wtf2 = (bf16*)take((size_t)H_DIM * FF_DIM * 2);
    float* ada1o = (float*)take((size_t)B_DIM * 2 * H_DIM * 4);
    float* ada2o = (float*)take((size_t)B_DIM * 2 * H_DIM * 4);
    bf16* h    = (bf16*)take((size_t)M_DIM * H_DIM * 2);
    bf16* qr   = (bf16*)take((size_t)M_DIM * H_DIM * 2);   // (B,NH,S,HD) bf16
    bf16* kr   = (bf16*)take((size_t)M_DIM * H_DIM * 2);   // (B,NH,S,HD) bf16
    f16*  vtf  = (f16*) take((size_t)M_DIM * H_DIM * 2);   // (B,NH,HD,S) f16
    bf16* attn = (bf16*)take((size_t)M_DIM * H_DIM * 2);   // (B,S,H) bf16
    float* x2  = (float*)take((size_t)M_DIM * H_DIM * 4);
    bf16* ff1b = qr;   // 32 MB GELU buffer aliases qr|kr|vtf|attn (dead by FF1 time)

    dim3 tb(32, 8);
    wtrans<<<dim3(32, 32),  tb, 0, stream>>>(wq,  wqkv,                 1024, 1024);
    wtrans<<<dim3(32, 32),  tb, 0, stream>>>(wk,  wqkv + 1024 * 1024,   1024, 1024);
    wtrans<<<dim3(32, 32),  tb, 0, stream>>>(wv,  wqkv + 2048 * 1024,   1024, 1024);
    wtrans<<<dim3(32, 32),  tb, 0, stream>>>(wo,  wto,  1024, 1024);
    wtrans<<<dim3(128, 32), tb, 0, stream>>>(fw1, wtf1, 1024, 4096);
    wtrans<<<dim3(32, 128), tb, 0, stream>>>(fw2, wtf2, 4096, 1024);

    ada_gemm<<<32, 256, 0, stream>>>(cond, ada1w, ada1b, ada2w, ada2b, ada1o, ada2o);
    adaln_k<<<M_DIM, 256, 0, stream>>>(x, ln1g, ln1b, ada1o, h);

    gemm_qkv<<<dim3(24, 32), 256, 0, stream>>>(h, wqkv, bq, bk, bv, qr, kr, vtf);

    flash<<<dim3(32, 16), 256, 0, stream>>>(qr, kr, vtf, attn);

    gemm_bt<EPI_RES><<<dim3(8, 32), 256, 0, stream>>>(attn, wto, bo, x, x2, M_DIM, H_DIM, H_DIM);

    adaln_k<<<M_DIM, 256, 0, stream>>>(x2, ln2g, ln2b, ada2o, h);

    gemm_bt<EPI_GELU><<<dim3(32, 32), 256, 0, stream>>>(h, wtf1, fb1, nullptr, ff1b, M_DIM, FF_DIM, H_DIM);
    gemm_bt<EPI_RES> <<<dim3(8, 32),  256, 0, stream>>>(ff1b, wtf2, fb2, x2, (float*)d_out, M_DIM, H_DIM, FF_DIM);

    (void)in_sizes; (void)n_in; (void)out_size; (void)ws_size;
}